// Round 3
// baseline (228.184 us; speedup 1.0000x reference)
//
#include <hip/hip_runtime.h>
#include <hip/hip_bf16.h>

#define BATCH 4
#define SEQ   2048
#define DIN   1024
#define DOUT  1024
#define N3    3072
#define MTOT  (BATCH*SEQ)

typedef __hip_bfloat16 bf16;
typedef __attribute__((ext_vector_type(8))) short bf16x8;
typedef __attribute__((ext_vector_type(4))) float f32x4;

#define MFMA(a,b,c) __builtin_amdgcn_mfma_f32_16x16x32_bf16(a,b,c,0,0,0)

union pack4 { bf16 h[4]; uint2 u2; };
union pack8 { bf16 h[8]; bf16x8 v; };

// async 16B global->LDS (DMA, no VGPR round-trip)
__device__ __forceinline__ void gl16(const bf16* g, bf16* l)
{
    __builtin_amdgcn_global_load_lds(
        (const __attribute__((address_space(1))) void*)g,
        (__attribute__((address_space(3))) void*)l, 16, 0, 0);
}

// ---------------- fused conversions (unchanged) ----------------

__global__ __launch_bounds__(256)
void k_prep(const float* __restrict__ x, const float* __restrict__ Wq,
            const float* __restrict__ Wk, const float* __restrict__ Wv,
            bf16* __restrict__ xb, bf16* __restrict__ Wt)
{
    __shared__ bf16 t[64][68];
    const int bid = blockIdx.x;
    if (bid < 8192) {
        long i = ((long)bid * 256 + threadIdx.x) * 4;
        float4 v = *(const float4*)(x + i);
        pack4 o;
        o.h[0] = __float2bfloat16(v.x);
        o.h[1] = __float2bfloat16(v.y);
        o.h[2] = __float2bfloat16(v.z);
        o.h[3] = __float2bfloat16(v.w);
        *(uint2*)(xb + i) = o.u2;
        return;
    }
    const int idx = bid - 8192;                // 0..767
    const int mat = idx >> 8;
    const int rem = idx & 255;
    const int k0 = (rem >> 4) * 64, n0 = (rem & 15) * 64;
    const float* W = (mat == 0) ? Wq : ((mat == 1) ? Wk : Wv);
#pragma unroll
    for (int p = 0; p < 4; ++p) {
        int kr = p * 16 + (threadIdx.x >> 4);
        int c4 = (threadIdx.x & 15) * 4;
        float4 v = *(const float4*)&W[(long)(k0 + kr) * DOUT + n0 + c4];
        t[c4 + 0][kr] = __float2bfloat16(v.x);
        t[c4 + 1][kr] = __float2bfloat16(v.y);
        t[c4 + 2][kr] = __float2bfloat16(v.z);
        t[c4 + 3][kr] = __float2bfloat16(v.w);
    }
    __syncthreads();
    bf16* O = Wt + (long)mat * DIN * DOUT;
#pragma unroll
    for (int i = 0; i < 2; ++i) {
        int l = threadIdx.x + i * 256;
        int n = l >> 3, c8 = (l & 7) * 8;
        pack8 o;
#pragma unroll
        for (int j = 0; j < 8; ++j) o.h[j] = t[n][c8 + j];
        *(bf16x8*)&O[(long)(n0 + n) * DIN + k0 + c8] = o.v;
    }
}

// ---------------- QKV: m201-geometry 256x256 8-phase core ----------------
// BM=BN=256, BK=64, 512 thr = 8 waves (2M x 4N), wave tile 128x64
// (acc[8][4] f32x4 = 128 f32). LDS 128 KiB: A[2][256][64] + B[2][256][64],
// XOR-chunk swizzle via pre-swizzled global source. 8 phases per iteration
// (2 K-tiles): each phase = {ds_reads for one C-quadrant | stage 1 half-tile
// (2 gl16) -> barrier -> 16 MFMA (setprio) -> barrier}. Counted vmcnt(4)
// only at end of phases 3 and 7.
//
// Staging ledger (iteration i: e=2i buf0, o=2i+1 buf1), 2 gl16 per half:
//   ph0: Ah0(o)   ph1: Ah1(o)   ph2: Bh0(e+2)  ph3: Bh1(e+2)  [WAIT vmcnt(4)]
//   ph4: Ah0(e+2) ph5: Ah1(e+2) ph6: Bh0(o+2)  ph7: Bh1(o+2)  [WAIT vmcnt(4)]
// Clobber-safe: each stage targets a region whose last ds_read retired at an
// earlier barrier (B(e) read ph0-1; A(e) read ph0,2; buf1 similarly ph4-6).
// WAIT_A outstanding list = [B(o)x4 (prev ph6,7), A(o)x4 (ph0,1), B(e+2)x4]
//   -> vmcnt(4) guarantees tile o fully landed before ph4-7 reads.
// WAIT_B outstanding = [B(e+2)x4, A(e+2)x4, B(o+2)x4] -> vmcnt(4) guarantees
//   tile e+2 landed before next iteration's ph0-3 reads.
// Last iteration (i=7): skip stages of tiles 16/17; WAIT_A -> vmcnt(0).

#define SBAR() do { __builtin_amdgcn_sched_barrier(0); \
                    __builtin_amdgcn_s_barrier();      \
                    __builtin_amdgcn_sched_barrier(0); } while (0)

#define RD_A(Ab, mg) do { _Pragma("unroll")                                    \
    for (int m_ = 0; m_ < 4; ++m_) {                                           \
        fa[m_][0] = *(const bf16x8*)&(Ab)[aBase + ((mg)+m_)*1024 + r*64 + slot0]; \
        fa[m_][1] = *(const bf16x8*)&(Ab)[aBase + ((mg)+m_)*1024 + r*64 + slot1]; \
    } } while (0)

#define RD_B(Bb, ng) do { _Pragma("unroll")                                    \
    for (int n_ = 0; n_ < 2; ++n_) {                                           \
        fb[(ng)+n_][0] = *(const bf16x8*)&(Bb)[bBase + ((ng)+n_)*1024 + r*64 + slot0]; \
        fb[(ng)+n_][1] = *(const bf16x8*)&(Bb)[bBase + ((ng)+n_)*1024 + r*64 + slot1]; \
    } } while (0)

#define MFMA_Q(mg, ng) do { __builtin_amdgcn_s_setprio(1);                     \
    _Pragma("unroll") for (int m_ = 0; m_ < 4; ++m_)                           \
    _Pragma("unroll") for (int n_ = 0; n_ < 2; ++n_) {                         \
        acc[(mg)+m_][(ng)+n_] = MFMA(fa[m_][0], fb[(ng)+n_][0], acc[(mg)+m_][(ng)+n_]); \
        acc[(mg)+m_][(ng)+n_] = MFMA(fa[m_][1], fb[(ng)+n_][1], acc[(mg)+m_][(ng)+n_]); \
    } __builtin_amdgcn_s_setprio(0); } while (0)

__global__ __launch_bounds__(512, 2)
void k_gemm_qkv(const bf16* __restrict__ xb, const bf16* __restrict__ Wt,
                bf16* __restrict__ QK, bf16* __restrict__ Vt)
{
    __shared__ __align__(16) bf16 smem[65536];      // 128 KiB
    bf16* sA = smem;                                 // [2][256][64]
    bf16* sB = smem + 32768;                         // [2][256][64]

    const int tid = threadIdx.x;
    // grid 384 = 32 m-tiles x 12 n-tiles; bijective XCD swizzle (384%8==0)
    const int wg  = blockIdx.y * 12 + blockIdx.x;
    const int swz = (wg & 7) * 48 + (wg >> 3);
    const int bx  = swz % 12, by = swz / 12;
    const int m0 = by * 256, n0 = bx * 256;

    const bf16* Ag = xb + (long)m0 * DIN;
    const bf16* Bg = Wt + (long)n0 * DIN;

    // staging geometry: one gl16 pass covers 64 rows x 64 cols (8 KiB)
    const int srow = tid >> 3;                       // 0..63
    const int scol = ((tid & 7) ^ (srow & 7)) * 8;   // pre-swizzled src chunk

    const int lane = tid & 63, wave = tid >> 6;
    const int wr = wave >> 2, wc = wave & 3;         // 2M x 4N wave grid
    const int r = lane & 15, qd = lane >> 4;
    const int aBase = (wr * 128) * 64;               // + mi*1024 + r*64
    const int bBase = (wc * 64) * 64;                // + ni*1024 + r*64
    const int slot0 = ( qd      ^ (r & 7)) * 8;      // ks=0
    const int slot1 = ((4 + qd) ^ (r & 7)) * 8;      // ks=1

    auto stA = [&](int t, int h, int p) {
        const bf16* src = Ag + (long)(h * 128 + p * 64 + srow) * DIN + t * 64 + scol;
        gl16(src, &sA[(t & 1) * 16384 + h * 8192 + p * 4096 + tid * 8]);
    };
    auto stB = [&](int t, int h, int p) {
        const bf16* src = Bg + (long)(h * 128 + p * 64 + srow) * DIN + t * 64 + scol;
        gl16(src, &sB[(t & 1) * 16384 + h * 8192 + p * 4096 + tid * 8]);
    };

    f32x4 acc[8][4] = {};
    bf16x8 fa[4][2], fb[4][2];

    // prologue: B(0), A(0), B(1); wait tile 0 (leave B(1)'s 4 in flight)
    stB(0,0,0); stB(0,0,1); stB(0,1,0); stB(0,1,1);
    stA(0,0,0); stA(0,0,1); stA(0,1,0); stA(0,1,1);
    stB(1,0,0); stB(1,0,1); stB(1,1,0); stB(1,1,1);
    asm volatile("s_waitcnt vmcnt(4)" ::: "memory");
    SBAR();

#pragma unroll 1
    for (int i = 0; i < 8; ++i) {
        const int e = 2 * i, o = e + 1;
        const bf16* A0 = sA;             // even tile buffer
        const bf16* B0 = sB;
        const bf16* A1 = sA + 16384;     // odd tile buffer
        const bf16* B1 = sB + 16384;
        const bool more = (i < 7);

        // ph0: tile e, Q(mi0-3, ni0-1)
        RD_A(A0, 0); RD_B(B0, 0);
        stA(o, 0, 0); stA(o, 0, 1);
        SBAR();
        MFMA_Q(0, 0);
        SBAR();

        // ph1: tile e, Q(mi0-3, ni2-3)
        RD_B(B0, 2);
        stA(o, 1, 0); stA(o, 1, 1);
        SBAR();
        MFMA_Q(0, 2);
        SBAR();

        // ph2: tile e, Q(mi4-7, ni0-1)
        RD_A(A0, 4);
        if (more) { stB(e + 2, 0, 0); stB(e + 2, 0, 1); }
        SBAR();
        MFMA_Q(4, 0);
        SBAR();

        // ph3: tile e, Q(mi4-7, ni2-3); WAIT_A
        if (more) { stB(e + 2, 1, 0); stB(e + 2, 1, 1); }
        SBAR();
        MFMA_Q(4, 2);
        __builtin_amdgcn_sched_barrier(0);
        if (more) { asm volatile("s_waitcnt vmcnt(4)" ::: "memory"); }
        else      { asm volatile("s_waitcnt vmcnt(0)" ::: "memory"); }
        SBAR();

        // ph4: tile o, Q(mi0-3, ni0-1)
        RD_A(A1, 0); RD_B(B1, 0);
        if (more) { stA(e + 2, 0, 0); stA(e + 2, 0, 1); }
        SBAR();
        MFMA_Q(0, 0);
        SBAR();

        // ph5: tile o, Q(mi0-3, ni2-3)
        RD_B(B1, 2);
        if (more) { stA(e + 2, 1, 0); stA(e + 2, 1, 1); }
        SBAR();
        MFMA_Q(0, 2);
        SBAR();

        // ph6: tile o, Q(mi4-7, ni0-1)
        RD_A(A1, 4);
        if (more) { stB(o + 2, 0, 0); stB(o + 2, 0, 1); }
        SBAR();
        MFMA_Q(4, 0);
        SBAR();

        // ph7: tile o, Q(mi4-7, ni2-3); WAIT_B
        if (more) { stB(o + 2, 1, 0); stB(o + 2, 1, 1); }
        SBAR();
        MFMA_Q(4, 2);
        __builtin_amdgcn_sched_barrier(0);
        if (more) { asm volatile("s_waitcnt vmcnt(4)" ::: "memory"); }
        SBAR();
    }

    // ---- epilogue ----
    if (bx < 8) {                                    // Q|K: direct store
#pragma unroll
        for (int mi = 0; mi < 8; ++mi)
#pragma unroll
            for (int ni = 0; ni < 4; ++ni)
#pragma unroll
                for (int j = 0; j < 4; ++j) {
                    int row = m0 + wr * 128 + mi * 16 + qd * 4 + j;
                    int col = n0 + wc * 64 + ni * 16 + r;
                    QK[(long)row * 2048 + col] = __float2bfloat16(acc[mi][ni][j]);
                }
    } else {                                         // V: transpose via LDS
        const int ld = 136;                          // 256*136 = 34816 elems
        bf16* T = smem;
        const int n0v = n0 - 2048;
        const int bb = m0 >> 11;
        const int s0 = m0 & 2047;
        bf16* Ob = Vt + (long)bb * DOUT * SEQ + s0;
#pragma unroll
        for (int h = 0; h < 2; ++h) {                // s-halves of 128
            if (h) __syncthreads();
            if (wr == h) {
#pragma unroll
                for (int mi = 0; mi < 8; ++mi)
#pragma unroll
                    for (int ni = 0; ni < 4; ++ni) {
                        pack4 p;
#pragma unroll
                        for (int j = 0; j < 4; ++j) p.h[j] = __float2bfloat16(acc[mi][ni][j]);
                        int d_l = wc * 64 + ni * 16 + r;     // 0..255
                        int s_l = mi * 16 + qd * 4;          // 0..127
                        *(uint2*)&T[d_l * ld + s_l] = p.u2;
                    }
            }
            __syncthreads();
#pragma unroll
            for (int p = 0; p < 8; ++p) {
                int l = tid + p * 512;               // 0..4095
                int d = l >> 4, s8 = (l & 15) * 8;
                bf16x8 vv = *(const bf16x8*)&T[d * ld + s8];
                *(bf16x8*)&Ob[(long)(n0v + d) * SEQ + s0 * 0 + h * 128 + s8] = vv;
            }
        }
    }
}

// ---------------- shared GEMM core (scores/pv), BK=64 ----------------

__device__ __forceinline__ void gemm_core(
    const bf16* __restrict__ Ab, long lda,
    const bf16* __restrict__ Bb, long ldb,
    int nk, bf16* __restrict__ As, bf16* __restrict__ Bs,
    f32x4 acc[4][4])
{
    const int tid  = threadIdx.x;
    const int lane = tid & 63;
    const int wave = tid >> 6;
    const int wm = (wave >> 1) * 64;
    const int wn = (wave & 1) * 64;
    const int r  = lane & 15;
    const int qd = lane >> 4;

    const int row0 = tid >> 3;                    // 0..31
    const int c    = (tid & 7) ^ (row0 & 7);      // swizzled source chunk
    const long aoff = (long)row0 * lda + c * 8;
    const long boff = (long)row0 * ldb + c * 8;
    const long astep = 32 * lda, bstep = 32 * ldb;
    bf16* dA = &As[tid * 8];
    bf16* dB = &Bs[tid * 8];

    for (int kk = 0; kk < nk; ++kk) {
        const bf16* A = Ab + kk * 64 + aoff;
        const bf16* B = Bb + kk * 64 + boff;
#pragma unroll
        for (int i = 0; i < 4; ++i) {
            gl16(A + i * astep, dA + i * 2048);
            gl16(B + i * bstep, dB + i * 2048);
        }
        __syncthreads();                           // drains vmcnt
#pragma unroll
        for (int ks = 0; ks < 2; ++ks) {
            const int slot = ((ks * 4 + qd) ^ (r & 7)) * 8;
            bf16x8 af[4], bv[4];
#pragma unroll
            for (int mi = 0; mi < 4; ++mi)
                af[mi] = *(const bf16x8*)&As[(wm + mi * 16 + r) * 64 + slot];
#pragma unroll
            for (int ni = 0; ni < 4; ++ni)
                bv[ni] = *(const bf16x8*)&Bs[(wn + ni * 16 + r) * 64 + slot];
#pragma unroll
            for (int mi = 0; mi < 4; ++mi)
#pragma unroll
                for (int ni = 0; ni < 4; ++ni)
                    acc[mi][ni] = MFMA(af[mi], bv[ni], acc[mi][ni]);
        }
        __syncthreads();
    }
}

// ---------------- scores + exp + row-sum (unchanged) ----------------

__global__ __launch_bounds__(256, 3)
void k_gemm_scores(const bf16* __restrict__ QK, bf16* __restrict__ P,
                   float* __restrict__ rowSum)
{
    const int b = blockIdx.z, qt = blockIdx.y, kt = blockIdx.x;
    if (kt > qt) return;
    __shared__ __align__(16) bf16 As[128 * 64];
    __shared__ __align__(16) bf16 Bs[128 * 64];
    const bf16* A  = QK + (long)b * SEQ * 2048;
    const bf16* Bt = A + 1024;
    f32x4 acc[4][4] = {};
    gemm_core(A + (long)qt * 128 * 2048, 2048, Bt + (long)kt * 128 * 2048, 2048,
              DIN / 64, As, Bs, acc);

    bf16* Pb = P + (long)b * SEQ * SEQ;
    float* RS = rowSum + b * SEQ;
    const int lane = threadIdx.x & 63, wave = threadIdx.x >> 6;
    const int wm = (wave >> 1) * 64, wn = (wave & 1) * 64;
    const int r = lane & 15, qd = lane >> 4;

    float rp[4][4];
#pragma unroll
    for (int mi = 0; mi < 4; ++mi)
#pragma unroll
        for (int j = 0; j < 4; ++j) rp[mi][j] = 0.f;

#pragma unroll
    for (int mi = 0; mi < 4; ++mi)
#pragma unroll
        for (int ni = 0; ni < 4; ++ni)
#pragma unroll
            for (int j = 0; j < 4; ++j) {
                int row = qt * 128 + wm + mi * 16 + qd * 4 + j;
                int col = kt * 128 + wn + ni * 16 + r;
                float e = (col > row) ? 0.f : __expf(acc[mi][ni][j] * 0.03125f);
                rp[mi][j] += e;
                Pb[(long)row * SEQ + col] = __float2bfloat16(e);
            }
#pragma unroll
    for (int d = 1; d < 16; d <<= 1)
#pragma unroll
        for (int mi = 0; mi < 4; ++mi)
#pragma unroll
            for (int j = 0; j < 4; ++j)
                rp[mi][j] += __shfl_xor(rp[mi][j], d, 64);
    if (r == 0) {
#pragma unroll
        for (int mi = 0; mi < 4; ++mi)
#pragma unroll
            for (int j = 0; j < 4; ++j) {
                int row = qt * 128 + wm + mi * 16 + qd * 4 + j;
                atomicAdd(&RS[row], rp[mi][j]);
            }
    }
}

// ---------------- PV: O = (P @ V) / rowSum (unchanged) ----------------

__global__ __launch_bounds__(256, 3)
void k_gemm_pv(const bf16* __restrict__ P, const bf16* __restrict__ Vt,
               const float* __restrict__ rowSum, float* __restrict__ O)
{
    const int b = blockIdx.z, nt = blockIdx.x;
    const int qt = (SEQ / 128 - 1) - blockIdx.y;   // heavy (large nk) first
    __shared__ __align__(16) bf16 As[128 * 64];
    __shared__ __align__(16) bf16 Bs[128 * 64];
    const bf16* A  = P + (long)b * SEQ * SEQ + (long)qt * 128 * SEQ;
    const bf16* Bt = Vt + (long)b * DOUT * SEQ;
    const int nk = (qt + 1) * 2;                   // K up to (qt+1)*128, BK=64
    f32x4 acc[4][4] = {};
    gemm_core(A, SEQ, Bt + (long)nt * 128 * SEQ, SEQ, nk, As, Bs, acc);

    float* Ob = O + (long)b * SEQ * DOUT;
    const float* RS = rowSum + b * SEQ;
    const int lane = threadIdx.x & 63, wave = threadIdx.x >> 6;
    const int wm = (wave >> 1) * 64, wn = (wave & 1) * 64;
    const int r = lane & 15, qd = lane >> 4;
#pragma unroll
    for (int mi = 0; mi < 4; ++mi)
#pragma unroll
        for (int j = 0; j < 4; ++j) {
            int row = qt * 128 + wm + mi * 16 + qd * 4 + j;
            float inv = 1.0f / RS[row];
#pragma unroll
            for (int ni = 0; ni < 4; ++ni) {
                int col = nt * 128 + wn + ni * 16 + r;
                Ob[(long)row * DOUT + col] = acc[mi][ni][j] * inv;
            }
        }
}

// ---------------- launch ----------------

extern "C" void kernel_launch(void* const* d_in, const int* in_sizes, int n_in,
                              void* d_out, int out_size, void* d_ws, size_t ws_size,
                              hipStream_t stream)
{
    const float* x  = (const float*)d_in[0];
    const float* Wq = (const float*)d_in[1];
    const float* Wk = (const float*)d_in[2];
    const float* Wv = (const float*)d_in[3];
    float* out = (float*)d_out;

    char* ws = (char*)d_ws;
    bf16*  xb = (bf16*)(ws);                        // 16 MiB
    bf16*  Wt = (bf16*)(ws + 16777216);             //  6 MiB
    bf16*  QK = (bf16*)(ws + 23068672);             // 32 MiB  [row][2048] = Q|K
    bf16*  Vt = (bf16*)(ws + 56623104);             // 16 MiB  [b][d][s]
    bf16*  P  = (bf16*)(ws + 73400320);             // 32 MiB
    float* RS = (float*)(ws + 106954752);           // 32 KiB  (total ~102 MiB)

    hipMemsetAsync(RS, 0, BATCH * SEQ * sizeof(float), stream);
    k_prep<<<dim3(8192 + 768), 256, 0, stream>>>(x, Wq, Wk, Wv, xb, Wt);
    k_gemm_qkv<<<dim3(12, 32), 512, 0, stream>>>(xb, Wt, QK, Vt);
    k_gemm_scores<<<dim3(SEQ / 128, SEQ / 128, BATCH), 256, 0, stream>>>(QK, P, RS);
    k_gemm_pv<<<dim3(DOUT / 128, SEQ / 128, BATCH), 256, 0, stream>>>(P, Vt, RS, out);
}

// Round 4
// 216.956 us; speedup vs baseline: 1.0518x; 1.0518x over previous
//
#include <hip/hip_runtime.h>
#include <hip/hip_bf16.h>

#define BATCH 4
#define SEQ   2048
#define DIN   1024
#define DOUT  1024
#define N3    3072
#define MTOT  (BATCH*SEQ)

typedef __hip_bfloat16 bf16;
typedef __attribute__((ext_vector_type(8))) short bf16x8;
typedef __attribute__((ext_vector_type(4))) float f32x4;

#define MFMA(a,b,c) __builtin_amdgcn_mfma_f32_16x16x32_bf16(a,b,c,0,0,0)

union pack4 { bf16 h[4]; uint2 u2; };
union pack8 { bf16 h[8]; bf16x8 v; };

// async 16B global->LDS (DMA, no VGPR round-trip)
__device__ __forceinline__ void gl16(const bf16* g, bf16* l)
{
    __builtin_amdgcn_global_load_lds(
        (const __attribute__((address_space(1))) void*)g,
        (__attribute__((address_space(3))) void*)l, 16, 0, 0);
}

// ---------------- fused conversions ----------------

__global__ __launch_bounds__(256)
void k_prep(const float* __restrict__ x, const float* __restrict__ Wq,
            const float* __restrict__ Wk, const float* __restrict__ Wv,
            bf16* __restrict__ xb, bf16* __restrict__ Wt)
{
    __shared__ bf16 t[64][68];
    const int bid = blockIdx.x;
    if (bid < 8192) {
        long i = ((long)bid * 256 + threadIdx.x) * 4;
        float4 v = *(const float4*)(x + i);
        pack4 o;
        o.h[0] = __float2bfloat16(v.x);
        o.h[1] = __float2bfloat16(v.y);
        o.h[2] = __float2bfloat16(v.z);
        o.h[3] = __float2bfloat16(v.w);
        *(uint2*)(xb + i) = o.u2;
        return;
    }
    const int idx = bid - 8192;                // 0..767
    const int mat = idx >> 8;
    const int rem = idx & 255;
    const int k0 = (rem >> 4) * 64, n0 = (rem & 15) * 64;
    const float* W = (mat == 0) ? Wq : ((mat == 1) ? Wk : Wv);
#pragma unroll
    for (int p = 0; p < 4; ++p) {
        int kr = p * 16 + (threadIdx.x >> 4);
        int c4 = (threadIdx.x & 15) * 4;
        float4 v = *(const float4*)&W[(long)(k0 + kr) * DOUT + n0 + c4];
        t[c4 + 0][kr] = __float2bfloat16(v.x);
        t[c4 + 1][kr] = __float2bfloat16(v.y);
        t[c4 + 2][kr] = __float2bfloat16(v.z);
        t[c4 + 3][kr] = __float2bfloat16(v.w);
    }
    __syncthreads();
    bf16* O = Wt + (long)mat * DIN * DOUT;
#pragma unroll
    for (int i = 0; i < 2; ++i) {
        int l = threadIdx.x + i * 256;
        int n = l >> 3, c8 = (l & 7) * 8;
        pack8 o;
#pragma unroll
        for (int j = 0; j < 8; ++j) o.h[j] = t[n][c8 + j];
        *(bf16x8*)&O[(long)(n0 + n) * DIN + k0 + c8] = o.v;
    }
}

// ---------------- shared GEMM core, BK=64 (round-0 verified) ----------------
// 128x128 tile, BK=64 (32 MFMA per barrier pair), 4 waves 2x2, each wave
// 64x64 via 4x4 mfma 16x16x32 over 2 k-steps. XOR-swizzled LDS (0 conflicts).

__device__ __forceinline__ void gemm_core(
    const bf16* __restrict__ Ab, long lda,
    const bf16* __restrict__ Bb, long ldb,
    int nk, bf16* __restrict__ As, bf16* __restrict__ Bs,
    f32x4 acc[4][4])
{
    const int tid  = threadIdx.x;
    const int lane = tid & 63;
    const int wave = tid >> 6;
    const int wm = (wave >> 1) * 64;
    const int wn = (wave & 1) * 64;
    const int r  = lane & 15;
    const int qd = lane >> 4;

    const int row0 = tid >> 3;                    // 0..31
    const int c    = (tid & 7) ^ (row0 & 7);      // swizzled source chunk
    const long aoff = (long)row0 * lda + c * 8;
    const long boff = (long)row0 * ldb + c * 8;
    const long astep = 32 * lda, bstep = 32 * ldb;
    bf16* dA = &As[tid * 8];
    bf16* dB = &Bs[tid * 8];

    for (int kk = 0; kk < nk; ++kk) {
        const bf16* A = Ab + kk * 64 + aoff;
        const bf16* B = Bb + kk * 64 + boff;
#pragma unroll
        for (int i = 0; i < 4; ++i) {
            gl16(A + i * astep, dA + i * 2048);
            gl16(B + i * bstep, dB + i * 2048);
        }
        __syncthreads();                           // drains vmcnt
#pragma unroll
        for (int ks = 0; ks < 2; ++ks) {
            const int slot = ((ks * 4 + qd) ^ (r & 7)) * 8;
            bf16x8 af[4], bv[4];
#pragma unroll
            for (int mi = 0; mi < 4; ++mi)
                af[mi] = *(const bf16x8*)&As[(wm + mi * 16 + r) * 64 + slot];
#pragma unroll
            for (int ni = 0; ni < 4; ++ni)
                bv[ni] = *(const bf16x8*)&Bs[(wn + ni * 16 + r) * 64 + slot];
#pragma unroll
            for (int mi = 0; mi < 4; ++mi)
#pragma unroll
                for (int ni = 0; ni < 4; ++ni)
                    acc[mi][ni] = MFMA(af[mi], bv[ni], acc[mi][ni]);
        }
        __syncthreads();
    }
}

// ---------------- QKV projection (round-0 verified) ----------------

__global__ __launch_bounds__(256)
void k_gemm_qkv(const bf16* __restrict__ xb, const bf16* __restrict__ Wt,
                bf16* __restrict__ QK, bf16* __restrict__ Vt)
{
    __shared__ __align__(16) bf16 smem[17408];    // 34.8 KB: As|Bs then T
    bf16* As = smem;
    bf16* Bs = smem + 8192;
    const int m0 = blockIdx.y * 128, n0 = blockIdx.x * 128;
    f32x4 acc[4][4] = {};
    gemm_core(xb + (long)m0 * DIN, DIN, Wt + (long)n0 * DIN, DIN, DIN / 64, As, Bs, acc);

    const int tid = threadIdx.x;
    const int lane = tid & 63, wave = tid >> 6;
    const int wm = (wave >> 1) * 64, wn = (wave & 1) * 64;
    const int r = lane & 15, qd = lane >> 4;

    if (n0 < 2048) {                               // Q|K: direct store
#pragma unroll
        for (int mi = 0; mi < 4; ++mi)
#pragma unroll
            for (int ni = 0; ni < 4; ++ni)
#pragma unroll
                for (int j = 0; j < 4; ++j) {
                    int row = m0 + wm + mi * 16 + qd * 4 + j;
                    int col = n0 + wn + ni * 16 + r;
                    QK[(long)row * 2048 + col] = __float2bfloat16(acc[mi][ni][j]);
                }
    } else {                                       // V: transpose via LDS
        const int ld = 136;                        // 16B-aligned row stride
        bf16* T = smem;                            // reuse (post-barrier)
#pragma unroll
        for (int mi = 0; mi < 4; ++mi)
#pragma unroll
            for (int ni = 0; ni < 4; ++ni) {
                pack4 p;
#pragma unroll
                for (int j = 0; j < 4; ++j) p.h[j] = __float2bfloat16(acc[mi][ni][j]);
                int d_l = wn + ni * 16 + r;
                int s_l = wm + mi * 16 + qd * 4;
                *(uint2*)&T[d_l * ld + s_l] = p.u2;
            }
        __syncthreads();
        const int n0v = n0 - 2048;
        const int bb = m0 >> 11;                   // batch index
        const int s0 = m0 & 2047;                  // seq offset within batch
        bf16* Ob = Vt + (long)bb * DOUT * SEQ + s0;
#pragma unroll
        for (int p = 0; p < 8; ++p) {
            int l = tid + p * 256;                 // 0..2047
            int d = l >> 4, s8 = (l & 15) * 8;
            bf16x8 vv = *(const bf16x8*)&T[d * ld + s8];
            *(bf16x8*)&Ob[(long)(n0v + d) * SEQ + s8] = vv;
        }
    }
}

// ---------------- scores + exp + row-sum ----------------
// Live-blocks-only grid: 544 = 4 batches x 136 lower-triangle tiles,
// heavy qt first, batches interleaved (i&3) so the tail is the light tiles.
// P written via LDS bounce -> b128 coalesced stores (was 64 scalar stores).

__global__ __launch_bounds__(256, 3)
void k_gemm_scores(const bf16* __restrict__ QK, bf16* __restrict__ P,
                   float* __restrict__ rowSum)
{
    const int bid = blockIdx.x;
    const int b = bid & 3;
    int rem = bid >> 2;                            // 0..135, heavy-first
    int qt = 15;
    while (rem > qt) { rem -= (qt + 1); --qt; }
    const int kt = rem;

    __shared__ __align__(16) bf16 smem[17408];     // As|Bs then bounce tile
    bf16* As = smem;
    bf16* Bs = smem + 8192;
    const bf16* A  = QK + (long)b * SEQ * 2048;
    const bf16* Bt = A + 1024;
    f32x4 acc[4][4] = {};
    gemm_core(A + (long)qt * 128 * 2048, 2048, Bt + (long)kt * 128 * 2048, 2048,
              DIN / 64, As, Bs, acc);

    bf16* Pb = P + (long)b * SEQ * SEQ;
    float* RS = rowSum + b * SEQ;
    const int tid = threadIdx.x;
    const int lane = tid & 63, wave = tid >> 6;
    const int wm = (wave >> 1) * 64, wn = (wave & 1) * 64;
    const int r = lane & 15, qd = lane >> 4;

    const int ld = 136;                            // bounce-tile stride
    bf16* T = smem;                                // reuse (post-barrier)

    float rp[4][4];
#pragma unroll
    for (int mi = 0; mi < 4; ++mi)
#pragma unroll
        for (int j = 0; j < 4; ++j) rp[mi][j] = 0.f;

#pragma unroll
    for (int mi = 0; mi < 4; ++mi)
#pragma unroll
        for (int ni = 0; ni < 4; ++ni)
#pragma unroll
            for (int j = 0; j < 4; ++j) {
                int row_l = wm + mi * 16 + qd * 4 + j;
                int col_l = wn + ni * 16 + r;
                int row = qt * 128 + row_l;
                int col = kt * 128 + col_l;
                float e = (col > row) ? 0.f : __expf(acc[mi][ni][j] * 0.03125f);
                rp[mi][j] += e;
                T[row_l * ld + col_l] = __float2bfloat16(e);
            }
#pragma unroll
    for (int d = 1; d < 16; d <<= 1)
#pragma unroll
        for (int mi = 0; mi < 4; ++mi)
#pragma unroll
            for (int j = 0; j < 4; ++j)
                rp[mi][j] += __shfl_xor(rp[mi][j], d, 64);
    if (r == 0) {
#pragma unroll
        for (int mi = 0; mi < 4; ++mi)
#pragma unroll
            for (int j = 0; j < 4; ++j) {
                int row = qt * 128 + wm + mi * 16 + qd * 4 + j;
                atomicAdd(&RS[row], rp[mi][j]);
            }
    }
    __syncthreads();
    // bulk coalesced P store: 128x128 tile, b128 per thread x8
#pragma unroll
    for (int p = 0; p < 8; ++p) {
        int l = tid + p * 256;                     // 0..2047
        int row_l = l >> 4, c8 = (l & 15) * 8;
        bf16x8 vv = *(const bf16x8*)&T[row_l * ld + c8];
        *(bf16x8*)&Pb[(long)(qt * 128 + row_l) * SEQ + kt * 128 + c8] = vv;
    }
}

// ---------------- PV: O = (P @ V) / rowSum ----------------
// Globally heavy-first linear grid: all (qt=15) blocks of all batches first.

__global__ __launch_bounds__(256, 3)
void k_gemm_pv(const bf16* __restrict__ P, const bf16* __restrict__ Vt,
               const float* __restrict__ rowSum, float* __restrict__ O)
{
    const int bid = blockIdx.x;                    // 0..511
    const int qt = 15 - (bid >> 5);                // heavy (large nk) first
    const int b  = (bid >> 3) & 3;
    const int nt = bid & 7;
    __shared__ __align__(16) bf16 As[128 * 64];
    __shared__ __align__(16) bf16 Bs[128 * 64];
    const bf16* A  = P + (long)b * SEQ * SEQ + (long)qt * 128 * SEQ;
    const bf16* Bt = Vt + (long)b * DOUT * SEQ;
    const int nk = (qt + 1) * 2;                   // K up to (qt+1)*128, BK=64
    f32x4 acc[4][4] = {};
    gemm_core(A, SEQ, Bt + (long)nt * 128 * SEQ, SEQ, nk, As, Bs, acc);

    float* Ob = O + (long)b * SEQ * DOUT;
    const float* RS = rowSum + b * SEQ;
    const int lane = threadIdx.x & 63, wave = threadIdx.x >> 6;
    const int wm = (wave >> 1) * 64, wn = (wave & 1) * 64;
    const int r = lane & 15, qd = lane >> 4;
#pragma unroll
    for (int mi = 0; mi < 4; ++mi)
#pragma unroll
        for (int j = 0; j < 4; ++j) {
            int row = qt * 128 + wm + mi * 16 + qd * 4 + j;
            float inv = 1.0f / RS[row];
#pragma unroll
            for (int ni = 0; ni < 4; ++ni) {
                int col = nt * 128 + wn + ni * 16 + r;
                Ob[(long)row * DOUT + col] = acc[mi][ni][j] * inv;
            }
        }
}

// ---------------- launch ----------------

extern "C" void kernel_launch(void* const* d_in, const int* in_sizes, int n_in,
                              void* d_out, int out_size, void* d_ws, size_t ws_size,
                              hipStream_t stream)
{
    const float* x  = (const float*)d_in[0];
    const float* Wq = (const float*)d_in[1];
    const float* Wk = (const float*)d_in[2];
    const float* Wv = (const float*)d_in[3];
    float* out = (float*)d_out;

    char* ws = (char*)d_ws;
    bf16*  xb = (bf16*)(ws);                        // 16 MiB
    bf16*  Wt = (bf16*)(ws + 16777216);             //  6 MiB
    bf16*  QK = (bf16*)(ws + 23068672);             // 32 MiB  [row][2048] = Q|K
    bf16*  Vt = (bf16*)(ws + 56623104);             // 16 MiB  [b][d][s]
    bf16*  P  = (bf16*)(ws + 73400320);             // 32 MiB
    float* RS = (float*)(ws + 106954752);           // 32 KiB  (total ~102 MiB)

    hipMemsetAsync(RS, 0, BATCH * SEQ * sizeof(float), stream);
    k_prep<<<dim3(8192 + 768), 256, 0, stream>>>(x, Wq, Wk, Wv, xb, Wt);
    k_gemm_qkv<<<dim3(N3 / 128, MTOT / 128), 256, 0, stream>>>(xb, Wt, QK, Vt);
    k_gemm_scores<<<dim3(544), 256, 0, stream>>>(QK, P, RS);
    k_gemm_pv<<<dim3(512), 256, 0, stream>>>(P, Vt, RS, out);
}